// Round 5
// baseline (77.376 us; speedup 1.0000x reference)
//
#include <hip/hip_runtime.h>
#include <hip/hip_bf16.h>

// MADPSNet fused: entire 4-layer expert-selected MLP in ONE kernel.
// Round 5: occupancy play. Round-4 evidence: Occ 19% (1 block/CU, LDS-capped),
// VGPR=108 proves compiler discarded the hand-rolled prefetch pipeline.
//  - 32-row blocks (512 blocks): LDS 48 KB -> 3 blocks/CU -> 12 waves/CU
//    (3 waves/SIMD, was 2) -> TLP hides L2 latency (m114)
//  - 256 thr = 4 waves, col-split 1x4; B weights read once per block
//    (B L2 traffic ~459 MB total; L1 reuse across 3 co-resident same-agent
//    blocks mitigates)
//  - plain unrolled k-loop, no hand multibuffering (compiler + TLP schedule)
//  - activations in LDS, XOR-swizzled both sides; agent = bid&7 -> XCD-pinned

typedef __attribute__((ext_vector_type(8))) short bf16x8;
typedef __attribute__((ext_vector_type(4))) float f32x4;

__device__ __forceinline__ ushort f2b(float x) {
    __hip_bfloat16 h = __float2bfloat16(x);
    return *reinterpret_cast<ushort*>(&h);
}

// swizzled LDS byte offset for bf16 (row, col); row stride = K elems (16B-chunk XOR)
__device__ __forceinline__ int swz_off(int row, int col, int K) {
    const int chunk = col >> 3;
    const int phys  = chunk ^ (row & 7);
    return row * (K * 2) + (phys << 4) + ((col & 7) << 1);
}

// ------------------------------------------------------------------ prep ---
// W[e][K][N] fp32 -> Wt[e][N][K] bf16 for all 4 layers, one kernel.
__global__ __launch_bounds__(256)
void prep_weights(const float* __restrict__ Ws1, const float* __restrict__ Ws2,
                  const float* __restrict__ Wd1, const float* __restrict__ Wd2,
                  ushort* __restrict__ W1t, ushort* __restrict__ W2t,
                  ushort* __restrict__ W3t, ushort* __restrict__ W4t)
{
    int t = blockIdx.x;
    const int e = blockIdx.z;
    const float* W; ushort* Wt; int K, N;
    if (t < 128)      { W = Ws1; Wt = W1t; K = 256; N = 512; }
    else if (t < 256) { t -= 128; W = Ws2; Wt = W2t; K = 512; N = 256; }
    else if (t < 384) { t -= 256; W = Wd1; Wt = W3t; K = 256; N = 512; }
    else              { t -= 384; W = Wd2; Wt = W4t; K = 512; N = 128; }
    W  += (size_t)e * K * N;
    Wt += (size_t)e * K * N;
    const int tn = N / 32;
    const int n0 = (t % tn) * 32;
    const int k0 = (t / tn) * 32;

    __shared__ float tile[32][33];
    const int tx = threadIdx.x;   // 0..31
    const int ty = threadIdx.y;   // 0..7
    #pragma unroll
    for (int j = 0; j < 4; ++j)
        tile[ty + j * 8][tx] = W[(size_t)(k0 + ty + j * 8) * N + n0 + tx];
    __syncthreads();
    #pragma unroll
    for (int j = 0; j < 4; ++j) {
        const int n = ty + j * 8;
        Wt[(size_t)(n0 + n) * K + k0 + tx] = f2b(tile[tx][n]);
    }
}

// ----------------------------------------------------------- fused layer ---
// A: LDS [32][K] bf16 swizzled. B: global Wt [N][K] bf16 (expert-selected).
// 4 waves split columns 1x4: wave wid owns cols [wid*N/4, (wid+1)*N/4).
template<int K, int N, int RELU>
__device__ __forceinline__ void layer_mlp(
    const ushort* __restrict__ Wt, const float* __restrict__ bias,
    const ushort* __restrict__ sIn, ushort* __restrict__ sOut,
    float* __restrict__ gOut, int wid, int lane)
{
    constexpr int F  = N / 64;           // 16-col frags per wave
    constexpr int NK = K / 32;           // k-steps
    const int r15 = lane & 15, lh = lane >> 4;
    const int wcol = wid * (N / 4);

    const ushort* bBase = Wt + (size_t)(wcol + r15) * K + lh * 8;

    f32x4 acc[2][F];
    #pragma unroll
    for (int m = 0; m < 2; ++m)
        #pragma unroll
        for (int f = 0; f < F; ++f)
            acc[m][f] = (f32x4){0.f, 0.f, 0.f, 0.f};

    #pragma unroll
    for (int s = 0; s < NK; ++s) {
        const int k0 = s * 32;
        bf16x8 a[2];
        #pragma unroll
        for (int m = 0; m < 2; ++m) {
            const int row  = m * 16 + r15;
            const int phys = ((k0 >> 3) + lh) ^ (row & 7);
            a[m] = *reinterpret_cast<const bf16x8*>(
                reinterpret_cast<const char*>(sIn) + row * (K * 2) + (phys << 4));
        }
        bf16x8 b[F];
        #pragma unroll
        for (int f = 0; f < F; ++f)
            b[f] = *reinterpret_cast<const bf16x8*>(bBase + (size_t)f * 16 * K + k0);
        #pragma unroll
        for (int m = 0; m < 2; ++m)
            #pragma unroll
            for (int f = 0; f < F; ++f)
                acc[m][f] = __builtin_amdgcn_mfma_f32_16x16x32_bf16(
                    a[m], b[f], acc[m][f], 0, 0, 0);
    }

    // epilogue
    #pragma unroll
    for (int f = 0; f < F; ++f) {
        const int col = wcol + f * 16 + r15;
        const float bv = bias[col];
        #pragma unroll
        for (int m = 0; m < 2; ++m) {
            #pragma unroll
            for (int j = 0; j < 4; ++j) {
                const int row = m * 16 + lh * 4 + j;   // C/D layout (m89)
                float v = acc[m][f][j] + bv;
                if (RELU) v = fmaxf(v, 0.f);
                if (gOut) {
                    gOut[(size_t)row * N + col] = v;
                } else {
                    *reinterpret_cast<ushort*>(
                        reinterpret_cast<char*>(sOut) + swz_off(row, col, N)) = f2b(v);
                }
            }
        }
    }
}

// ----------------------------------------------------------- fused kernel ---
__global__ __launch_bounds__(256, 3)
void madps_fused(const float* __restrict__ X,
                 const int* __restrict__ sel_s, const int* __restrict__ sel_d,
                 const ushort* __restrict__ W1t, const ushort* __restrict__ W2t,
                 const ushort* __restrict__ W3t, const ushort* __restrict__ W4t,
                 const float* __restrict__ bs1, const float* __restrict__ bs2,
                 const float* __restrict__ bd1, const float* __restrict__ bd2,
                 float* __restrict__ out)
{
    constexpr int S = 256, H1 = 512, H2 = 256, D1 = 512, D2 = 128;
    constexpr int RB = 32;              // rows per block

    __shared__ __align__(16) ushort buf0[RB * 256];   // 16 KB: X, then sh
    __shared__ __align__(16) ushort buf1[RB * 512];   // 32 KB: h, then d

    const int bid   = blockIdx.x;
    const int agent = bid & 7;          // agent == XCD -> weights L2-resident
    const int rb    = bid >> 3;         // row-block within agent (0..63)
    const int tid   = threadIdx.x;
    const int lane  = tid & 63;
    const int wid   = tid >> 6;         // 0..3

    const long long es = sel_s[agent];
    const long long ed = sel_d[agent];

    const float* Xa = X + ((size_t)agent * 2048 + (size_t)rb * RB) * S;

    // ---- stage X [32][256] fp32 -> buf0 bf16 (swizzled) ----
    #pragma unroll
    for (int i = 0; i < 8; ++i) {
        const int flat4 = i * 256 + tid;        // float4 index, 64/row
        const int row = flat4 >> 6;
        const int c4  = flat4 & 63;
        const float4 v = reinterpret_cast<const float4*>(Xa)[flat4];
        ushort4 o;
        o.x = f2b(v.x); o.y = f2b(v.y); o.z = f2b(v.z); o.w = f2b(v.w);
        const int byteoff = (((c4 >> 1) ^ (row & 7)) << 4) | ((c4 & 1) << 3);
        *reinterpret_cast<ushort4*>(
            reinterpret_cast<char*>(buf0) + row * 512 + byteoff) = o;
    }
    __syncthreads();

    // L1: X(buf0, K=256) @ W1t -> relu -> h(buf1, N=512)
    layer_mlp<S, H1, 1>(W1t + es * (S * H1), bs1 + es * H1,
                        buf0, buf1, nullptr, wid, lane);
    __syncthreads();
    // L2: h(buf1, K=512) @ W2t -> relu -> sh(buf0, N=256)
    layer_mlp<H1, H2, 1>(W2t + es * (H1 * H2), bs2 + es * H2,
                         buf1, buf0, nullptr, wid, lane);
    __syncthreads();
    // L3: sh(buf0, K=256) @ W3t -> relu -> d(buf1, N=512)
    layer_mlp<H2, D1, 1>(W3t + ed * (H2 * D1), bd1 + ed * D1,
                         buf0, buf1, nullptr, wid, lane);
    __syncthreads();
    // L4: d(buf1, K=512) @ W4t + bias -> out fp32 [32][128]
    float* outP = out + ((size_t)agent * 2048 + (size_t)rb * RB) * D2;
    layer_mlp<D1, D2, 0>(W4t + ed * (D1 * D2), bd2 + ed * D2,
                         buf1, nullptr, outP, wid, lane);
}

// --------------------------------------------------------------- launch ---
extern "C" void kernel_launch(void* const* d_in, const int* in_sizes, int n_in,
                              void* d_out, int out_size, void* d_ws, size_t ws_size,
                              hipStream_t stream)
{
    constexpr int E = 8, S = 256, H1 = 512, H2 = 256, D1 = 512, D2 = 128;

    const float* inputs = (const float*)d_in[0];
    const int*   sel_s  = (const int*)d_in[1];
    const int*   sel_d  = (const int*)d_in[2];
    const float* Ws1 = (const float*)d_in[3];
    const float* bs1 = (const float*)d_in[4];
    const float* Ws2 = (const float*)d_in[5];
    const float* bs2 = (const float*)d_in[6];
    const float* Wd1 = (const float*)d_in[7];
    const float* bd1 = (const float*)d_in[8];
    const float* Wd2 = (const float*)d_in[9];
    const float* bd2 = (const float*)d_in[10];
    float* out = (float*)d_out;

    // workspace: transposed bf16 weights only
    ushort* W1t = (ushort*)d_ws;                     // [E][H1][S]
    ushort* W2t = W1t + (size_t)E * S * H1;          // [E][H2][H1]
    ushort* W3t = W2t + (size_t)E * H1 * H2;         // [E][D1][H2]
    ushort* W4t = W3t + (size_t)E * H2 * D1;         // [E][D2][D1]

    prep_weights<<<dim3(448, 1, E), dim3(32, 8), 0, stream>>>(
        Ws1, Ws2, Wd1, Wd2, W1t, W2t, W3t, W4t);

    madps_fused<<<dim3(512), dim3(256), 0, stream>>>(
        inputs, sel_s, sel_d, W1t, W2t, W3t, W4t,
        bs1, bs2, bd1, bd2, out);
}

// Round 6
// 45.697 us; speedup vs baseline: 1.6933x; 1.6933x over previous
//
#include <hip/hip_runtime.h>
#include <hip/hip_bf16.h>

// MADPSNet fused: entire 4-layer expert-selected MLP in ONE kernel.
// Round 6: round-4 geometry (M=64, 512 thr, 8 waves, col-split 1x8, B read
// once per block) + FORCED register pipeline:
//  - B prefetched 2 k-steps ahead (3 bufs), A 1 step (2 bufs)
//  - __builtin_amdgcn_sched_barrier(0) between prefetch block and MFMA
//    cluster pins issue order (round-4 VGPR=108 proved the compiler
//    collapsed the un-fenced pipeline; need >=144 live VGPRs)
//  - s_setprio(1) around MFMA cluster (waves drift between layer barriers
//    -> role diversity -> T5 applies)
//  - activations in LDS (96 KB), XOR-swizzled both sides
//  - agent = bid&7 -> one agent's ~918 KB bf16 weights resident per XCD L2

typedef __attribute__((ext_vector_type(8))) short bf16x8;
typedef __attribute__((ext_vector_type(4))) float f32x4;

__device__ __forceinline__ ushort f2b(float x) {
    __hip_bfloat16 h = __float2bfloat16(x);
    return *reinterpret_cast<ushort*>(&h);
}

// swizzled LDS byte offset for bf16 (row, col); row stride = K elems (16B-chunk XOR)
__device__ __forceinline__ int swz_off(int row, int col, int K) {
    const int chunk = col >> 3;
    const int phys  = chunk ^ (row & 7);
    return row * (K * 2) + (phys << 4) + ((col & 7) << 1);
}

// ------------------------------------------------------------------ prep ---
// W[e][K][N] fp32 -> Wt[e][N][K] bf16 for all 4 layers, one kernel.
__global__ __launch_bounds__(256)
void prep_weights(const float* __restrict__ Ws1, const float* __restrict__ Ws2,
                  const float* __restrict__ Wd1, const float* __restrict__ Wd2,
                  ushort* __restrict__ W1t, ushort* __restrict__ W2t,
                  ushort* __restrict__ W3t, ushort* __restrict__ W4t)
{
    int t = blockIdx.x;
    const int e = blockIdx.z;
    const float* W; ushort* Wt; int K, N;
    if (t < 128)      { W = Ws1; Wt = W1t; K = 256; N = 512; }
    else if (t < 256) { t -= 128; W = Ws2; Wt = W2t; K = 512; N = 256; }
    else if (t < 384) { t -= 256; W = Wd1; Wt = W3t; K = 256; N = 512; }
    else              { t -= 384; W = Wd2; Wt = W4t; K = 512; N = 128; }
    W  += (size_t)e * K * N;
    Wt += (size_t)e * K * N;
    const int tn = N / 32;
    const int n0 = (t % tn) * 32;
    const int k0 = (t / tn) * 32;

    __shared__ float tile[32][33];
    const int tx = threadIdx.x;   // 0..31
    const int ty = threadIdx.y;   // 0..7
    #pragma unroll
    for (int j = 0; j < 4; ++j)
        tile[ty + j * 8][tx] = W[(size_t)(k0 + ty + j * 8) * N + n0 + tx];
    __syncthreads();
    #pragma unroll
    for (int j = 0; j < 4; ++j) {
        const int n = ty + j * 8;
        Wt[(size_t)(n0 + n) * K + k0 + tx] = f2b(tile[tx][n]);
    }
}

// ----------------------------------------------------------- fused layer ---
// A: LDS [64][K] bf16 swizzled. B: global Wt [N][K] bf16 (expert-selected).
// Wave `wid` owns cols [wid*N/8, (wid+1)*N/8). F = N/128 col-frags.
template<int K, int N, int RELU>
__device__ __forceinline__ void layer_mlp(
    const ushort* __restrict__ Wt, const float* __restrict__ bias,
    const ushort* __restrict__ sIn, ushort* __restrict__ sOut,
    float* __restrict__ gOut, int wid, int lane)
{
    constexpr int F  = N / 128;          // col frags per wave
    constexpr int NK = K / 32;           // k-steps
    const int r15 = lane & 15, lh = lane >> 4;
    const int wcol = wid * (N / 8);

    // lane base for B: col = wcol + f*16 + r15, elems k0 + lh*8
    const ushort* bBase = Wt + (size_t)(wcol + r15) * K + lh * 8;

    f32x4 acc[4][F];
    #pragma unroll
    for (int m = 0; m < 4; ++m)
        #pragma unroll
        for (int f = 0; f < F; ++f)
            acc[m][f] = (f32x4){0.f, 0.f, 0.f, 0.f};

    bf16x8 a[2][4], b[3][F];

    auto loadA = [&](int buf, int k0) {
        #pragma unroll
        for (int m = 0; m < 4; ++m) {
            const int row  = m * 16 + r15;
            const int phys = ((k0 >> 3) + lh) ^ (row & 7);
            a[buf][m] = *reinterpret_cast<const bf16x8*>(
                reinterpret_cast<const char*>(sIn) + row * (K * 2) + (phys << 4));
        }
    };
    auto loadB = [&](int buf, int k0) {
        #pragma unroll
        for (int f = 0; f < F; ++f)
            b[buf][f] = *reinterpret_cast<const bf16x8*>(
                bBase + (size_t)f * 16 * K + k0);
    };

    // prologue: B 2 steps deep, A 1 step
    loadB(0, 0);
    if (NK > 1) loadB(1, 32);
    loadA(0, 0);

    #pragma unroll
    for (int s = 0; s < NK; ++s) {
        if (s + 2 < NK) loadB((s + 2) % 3, (s + 2) * 32);
        if (s + 1 < NK) loadA((s + 1) & 1, (s + 1) * 32);
        // pin: prefetch issues BEFORE this point, MFMAs after. Without this
        // fence the scheduler collapses the pipeline (r4: VGPR=108 < 144).
        __builtin_amdgcn_sched_barrier(0);
        __builtin_amdgcn_s_setprio(1);
        #pragma unroll
        for (int m = 0; m < 4; ++m)
            #pragma unroll
            for (int f = 0; f < F; ++f)
                acc[m][f] = __builtin_amdgcn_mfma_f32_16x16x32_bf16(
                    a[s & 1][m], b[s % 3][f], acc[m][f], 0, 0, 0);
        __builtin_amdgcn_s_setprio(0);
    }

    // epilogue
    #pragma unroll
    for (int f = 0; f < F; ++f) {
        const int col = wcol + f * 16 + r15;
        const float bv = bias[col];
        #pragma unroll
        for (int m = 0; m < 4; ++m) {
            #pragma unroll
            for (int j = 0; j < 4; ++j) {
                const int row = m * 16 + lh * 4 + j;   // C/D layout (m89)
                float v = acc[m][f][j] + bv;
                if (RELU) v = fmaxf(v, 0.f);
                if (gOut) {
                    gOut[(size_t)row * N + col] = v;
                } else {
                    *reinterpret_cast<ushort*>(
                        reinterpret_cast<char*>(sOut) + swz_off(row, col, N)) = f2b(v);
                }
            }
        }
    }
}

// ----------------------------------------------------------- fused kernel ---
__global__ __launch_bounds__(512, 2)
void madps_fused(const float* __restrict__ X,
                 const int* __restrict__ sel_s, const int* __restrict__ sel_d,
                 const ushort* __restrict__ W1t, const ushort* __restrict__ W2t,
                 const ushort* __restrict__ W3t, const ushort* __restrict__ W4t,
                 const float* __restrict__ bs1, const float* __restrict__ bs2,
                 const float* __restrict__ bd1, const float* __restrict__ bd2,
                 float* __restrict__ out)
{
    constexpr int S = 256, H1 = 512, H2 = 256, D1 = 512, D2 = 128;

    __shared__ __align__(16) ushort buf0[64 * 256];   // 32 KB: X, then sh
    __shared__ __align__(16) ushort buf1[64 * 512];   // 64 KB: h, then d

    const int bid   = blockIdx.x;
    const int agent = bid & 7;          // agent == XCD -> weights L2-resident
    const int rb    = bid >> 3;         // row-block within agent (0..31)
    const int tid   = threadIdx.x;
    const int lane  = tid & 63;
    const int wid   = tid >> 6;         // 0..7

    const long long es = sel_s[agent];
    const long long ed = sel_d[agent];

    const float* Xa = X + ((size_t)agent * 2048 + (size_t)rb * 64) * S;

    // ---- stage X [64][256] fp32 -> buf0 bf16 (swizzled) ----
    #pragma unroll
    for (int i = 0; i < 8; ++i) {
        const int flat4 = i * 512 + tid;        // float4 index, 64/row
        const int row = flat4 >> 6;
        const int c4  = flat4 & 63;
        const float4 v = reinterpret_cast<const float4*>(Xa)[flat4];
        ushort4 o;
        o.x = f2b(v.x); o.y = f2b(v.y); o.z = f2b(v.z); o.w = f2b(v.w);
        const int byteoff = (((c4 >> 1) ^ (row & 7)) << 4) | ((c4 & 1) << 3);
        *reinterpret_cast<ushort4*>(
            reinterpret_cast<char*>(buf0) + row * 512 + byteoff) = o;
    }
    __syncthreads();

    // L1: X(buf0, K=256) @ W1t -> relu -> h(buf1, N=512)
    layer_mlp<S, H1, 1>(W1t + es * (S * H1), bs1 + es * H1,
                        buf0, buf1, nullptr, wid, lane);
    __syncthreads();
    // L2: h(buf1, K=512) @ W2t -> relu -> sh(buf0, N=256)
    layer_mlp<H1, H2, 1>(W2t + es * (H1 * H2), bs2 + es * H2,
                         buf1, buf0, nullptr, wid, lane);
    __syncthreads();
    // L3: sh(buf0, K=256) @ W3t -> relu -> d(buf1, N=512)
    layer_mlp<H2, D1, 1>(W3t + ed * (H2 * D1), bd1 + ed * D1,
                         buf0, buf1, nullptr, wid, lane);
    __syncthreads();
    // L4: d(buf1, K=512) @ W4t + bias -> out fp32 [64][128]
    float* outP = out + ((size_t)agent * 2048 + (size_t)rb * 64) * D2;
    layer_mlp<D1, D2, 0>(W4t + ed * (D1 * D2), bd2 + ed * D2,
                         buf1, nullptr, outP, wid, lane);
}

// --------------------------------------------------------------- launch ---
extern "C" void kernel_launch(void* const* d_in, const int* in_sizes, int n_in,
                              void* d_out, int out_size, void* d_ws, size_t ws_size,
                              hipStream_t stream)
{
    constexpr int E = 8, S = 256, H1 = 512, H2 = 256, D1 = 512, D2 = 128;

    const float* inputs = (const float*)d_in[0];
    const int*   sel_s  = (const int*)d_in[1];
    const int*   sel_d  = (const int*)d_in[2];
    const float* Ws1 = (const float*)d_in[3];
    const float* bs1 = (const float*)d_in[4];
    const float* Ws2 = (const float*)d_in[5];
    const float* bs2 = (const float*)d_in[6];
    const float* Wd1 = (const float*)d_in[7];
    const float* bd1 = (const float*)d_in[8];
    const float* Wd2 = (const float*)d_in[9];
    const float* bd2 = (const float*)d_in[10];
    float* out = (float*)d_out;

    // workspace: transposed bf16 weights only
    ushort* W1t = (ushort*)d_ws;                     // [E][H1][S]
    ushort* W2t = W1t + (size_t)E * S * H1;          // [E][H2][H1]
    ushort* W3t = W2t + (size_t)E * H1 * H2;         // [E][D1][H2]
    ushort* W4t = W3t + (size_t)E * H2 * D1;         // [E][D2][D1]

    prep_weights<<<dim3(448, 1, E), dim3(32, 8), 0, stream>>>(
        Ws1, Ws2, Wd1, Wd2, W1t, W2t, W3t, W4t);

    madps_fused<<<dim3(256), dim3(512), 0, stream>>>(
        inputs, sel_s, sel_d, W1t, W2t, W3t, W4t,
        bs1, bs2, bd1, bd2, out);
}

// Round 7
// 43.184 us; speedup vs baseline: 1.7918x; 1.0582x over previous
//
#include <hip/hip_runtime.h>
#include <hip/hip_bf16.h>

// MADPSNet fused, round 7.
// r4/r6 post-mortem: 40 us wall is latency exposure; scheduling fences were
// null (13% MfmaUtil both). Per-CU resource floors: MFMA 17.4kcy, B-from-L2
// 16kcy, A-from-LDS 18kcy -> balanced ~7.5us. Attack latency two ways:
//  1) FRAGMENT-PACKED weights: prep emits B in MFMA fragment order
//     [fg][kstep][lane][8] -> every B-load is a contiguous coalesced 1KB
//     wave-stream (was 16 scattered 64B lines -> suspected MSHR exhaustion).
//  2) 1024 threads = 16 waves = 4 waves/SIMD TLP (m114: wave overlap is the
//     latency-hiding that works). Col-split 1x16 keeps B read once/block.
// Activations in LDS (96 KB), XOR-swizzled; agent = bid&7 (XCD-pinned).

typedef __attribute__((ext_vector_type(8))) short bf16x8;
typedef __attribute__((ext_vector_type(4))) float f32x4;

__device__ __forceinline__ ushort f2b(float x) {
    __hip_bfloat16 h = __float2bfloat16(x);
    return *reinterpret_cast<ushort*>(&h);
}

// swizzled LDS byte offset for bf16 (row, col); row stride = LD elems
__device__ __forceinline__ int swz_off(int row, int col, int LD) {
    const int chunk = col >> 3;
    const int phys  = chunk ^ (row & 7);
    return row * (LD * 2) + (phys << 4) + ((col & 7) << 1);
}

// ------------------------------------------------------------------ prep ---
// W[e][K][N] fp32 -> Wp[e][fg][s][lane][j] bf16 (MFMA fragment order):
//   n = fg*16 + (lane&15), k = s*32 + (lane>>4)*8 + j,  s = 0..K/32-1
__global__ __launch_bounds__(256)
void prep_weights(const float* __restrict__ Ws1, const float* __restrict__ Ws2,
                  const float* __restrict__ Wd1, const float* __restrict__ Wd2,
                  ushort* __restrict__ W1p, ushort* __restrict__ W2p,
                  ushort* __restrict__ W3p, ushort* __restrict__ W4p)
{
    const int layer = blockIdx.z;
    const int e  = blockIdx.y;
    const int fg = blockIdx.x;
    const float* W; ushort* Wp; int K, N;
    if (layer == 0)      { W = Ws1; Wp = W1p; K = 256; N = 512; }
    else if (layer == 1) { W = Ws2; Wp = W2p; K = 512; N = 256; }
    else if (layer == 2) { W = Wd1; Wp = W3p; K = 256; N = 512; }
    else                 { W = Wd2; Wp = W4p; K = 512; N = 128; }
    if (fg >= N / 16) return;
    const int NK = K / 32;
    W += (size_t)e * K * N;

    __shared__ float tile[512][17];
    const int tid = threadIdx.x;
    const int n0 = fg * 16;
    // stage W[:, n0:n0+16] (coalesced 16-lane rows)
    for (int idx = tid; idx < K * 16; idx += 256)
        tile[idx >> 4][idx & 15] = W[(size_t)(idx >> 4) * N + n0 + (idx & 15)];
    __syncthreads();
    // emit packed fragments (64-lane contiguous 1KB stores)
    ushort* dst = Wp + (((size_t)e * (N / 16) + fg) * NK) * 512;
    for (int w = tid; w < NK * 64; w += 256) {
        const int s    = w >> 6;
        const int lane = w & 63;
        const int c    = lane & 15;
        const int kb   = s * 32 + ((lane >> 4) << 3);
        bf16x8 v;
        #pragma unroll
        for (int j = 0; j < 8; ++j)
            v[j] = (short)f2b(tile[kb + j][c]);
        *reinterpret_cast<bf16x8*>(&dst[(size_t)w * 8]) = v;
    }
}

// ----------------------------------------------------------- fused layer ---
// A: LDS [64][K] bf16 swizzled. B: packed global (fragment order).
// 16 waves: MG row-groups x NG col-groups (MG*NG=16), F=N/16/NG frags/wave.
template<int K, int N, int MG, int RELU>
__device__ __forceinline__ void layer_mlp(
    const ushort* __restrict__ Wp, const float* __restrict__ bias,
    const ushort* __restrict__ sIn, ushort* __restrict__ sOut,
    float* __restrict__ gOut, int wid, int lane)
{
    constexpr int NG = 16 / MG;          // col groups
    constexpr int F  = N / 16 / NG;      // frags per wave
    constexpr int M4 = 4 / MG;           // m-frags per wave
    constexpr int NK = K / 32;           // k-steps
    const int r15 = lane & 15, lh = lane >> 4;
    const int wc = wid % NG, wr = wid / NG;
    const int rowBase = wr * (64 / MG);

    // packed B base for this wave: fg = wc*F + f
    const ushort* bBase = Wp + ((size_t)(wc * F) * NK) * 512 + (size_t)lane * 8;

    f32x4 acc[M4][F];
    #pragma unroll
    for (int m = 0; m < M4; ++m)
        #pragma unroll
        for (int f = 0; f < F; ++f)
            acc[m][f] = (f32x4){0.f, 0.f, 0.f, 0.f};

    bf16x8 a[2][M4], b[3][F];

    auto loadA = [&](int buf, int k0) {
        #pragma unroll
        for (int m = 0; m < M4; ++m) {
            const int row  = rowBase + m * 16 + r15;
            const int phys = ((k0 >> 3) + lh) ^ (row & 7);
            a[buf][m] = *reinterpret_cast<const bf16x8*>(
                reinterpret_cast<const char*>(sIn) + row * (K * 2) + (phys << 4));
        }
    };
    auto loadB = [&](int buf, int s) {
        #pragma unroll
        for (int f = 0; f < F; ++f)
            b[buf][f] = *reinterpret_cast<const bf16x8*>(
                bBase + ((size_t)f * NK + s) * 512);
    };

    loadB(0, 0);
    if (NK > 1) loadB(1, 1);
    loadA(0, 0);

    #pragma unroll
    for (int s = 0; s < NK; ++s) {
        if (s + 2 < NK) loadB((s + 2) % 3, s + 2);
        if (s + 1 < NK) loadA((s + 1) & 1, (s + 1) * 32);
        __builtin_amdgcn_sched_barrier(0);
        __builtin_amdgcn_s_setprio(1);
        #pragma unroll
        for (int m = 0; m < M4; ++m)
            #pragma unroll
            for (int f = 0; f < F; ++f)
                acc[m][f] = __builtin_amdgcn_mfma_f32_16x16x32_bf16(
                    a[s & 1][m], b[s % 3][f], acc[m][f], 0, 0, 0);
        __builtin_amdgcn_s_setprio(0);
    }

    // epilogue
    #pragma unroll
    for (int f = 0; f < F; ++f) {
        const int col = (wc * F + f) * 16 + r15;
        const float bv = bias[col];
        #pragma unroll
        for (int m = 0; m < M4; ++m) {
            #pragma unroll
            for (int j = 0; j < 4; ++j) {
                const int row = rowBase + m * 16 + lh * 4 + j;   // C/D (m89)
                float v = acc[m][f][j] + bv;
                if (RELU) v = fmaxf(v, 0.f);
                if (gOut) {
                    gOut[(size_t)row * N + col] = v;
                } else {
                    *reinterpret_cast<ushort*>(
                        reinterpret_cast<char*>(sOut) + swz_off(row, col, N)) = f2b(v);
                }
            }
        }
    }
}

// ----------------------------------------------------------- fused kernel ---
__global__ __launch_bounds__(1024, 4)
void madps_fused(const float* __restrict__ X,
                 const int* __restrict__ sel_s, const int* __restrict__ sel_d,
                 const ushort* __restrict__ W1p, const ushort* __restrict__ W2p,
                 const ushort* __restrict__ W3p, const ushort* __restrict__ W4p,
                 const float* __restrict__ bs1, const float* __restrict__ bs2,
                 const float* __restrict__ bd1, const float* __restrict__ bd2,
                 float* __restrict__ out)
{
    constexpr int S = 256, H1 = 512, H2 = 256, D1 = 512, D2 = 128;

    __shared__ __align__(16) ushort buf0[64 * 256];   // 32 KB: X, then sh
    __shared__ __align__(16) ushort buf1[64 * 512];   // 64 KB: h, then d

    const int bid   = blockIdx.x;
    const int agent = bid & 7;          // agent == XCD -> weights L2-resident
    const int rb    = bid >> 3;         // row-block within agent (0..31)
    const int tid   = threadIdx.x;
    const int lane  = tid & 63;
    const int wid   = tid >> 6;         // 0..15

    const long long es = sel_s[agent];
    const long long ed = sel_d[agent];

    const float* Xa = X + ((size_t)agent * 2048 + (size_t)rb * 64) * S;

    // ---- stage X [64][256] fp32 -> buf0 bf16 (swizzled) ----
    #pragma unroll
    for (int i = 0; i < 4; ++i) {
        const int flat4 = i * 1024 + tid;       // float4 index, 64/row
        const int row = flat4 >> 6;
        const int c4  = flat4 & 63;
        const float4 v = reinterpret_cast<const float4*>(Xa)[flat4];
        ushort4 o;
        o.x = f2b(v.x); o.y = f2b(v.y); o.z = f2b(v.z); o.w = f2b(v.w);
        const int byteoff = (((c4 >> 1) ^ (row & 7)) << 4) | ((c4 & 1) << 3);
        *reinterpret_cast<ushort4*>(
            reinterpret_cast<char*>(buf0) + row * 512 + byteoff) = o;
    }
    __syncthreads();

    // L1: X(buf0, K=256) @ W1p -> relu -> h(buf1, N=512)
    layer_mlp<S, H1, 1, 1>(W1p + (size_t)es * ((H1 / 16) * (S / 32) * 512),
                           bs1 + es * H1, buf0, buf1, nullptr, wid, lane);
    __syncthreads();
    // L2: h(buf1, K=512) @ W2p -> relu -> sh(buf0, N=256)
    layer_mlp<H1, H2, 1, 1>(W2p + (size_t)es * ((H2 / 16) * (H1 / 32) * 512),
                            bs2 + es * H2, buf1, buf0, nullptr, wid, lane);
    __syncthreads();
    // L3: sh(buf0, K=256) @ W3p -> relu -> d(buf1, N=512)
    layer_mlp<H2, D1, 1, 1>(W3p + (size_t)ed * ((D1 / 16) * (H2 / 32) * 512),
                            bd1 + ed * D1, buf0, buf1, nullptr, wid, lane);
    __syncthreads();
    // L4: d(buf1, K=512) @ W4p + bias -> out fp32 [64][128]  (2x8 M-split)
    float* outP = out + ((size_t)agent * 2048 + (size_t)rb * 64) * D2;
    layer_mlp<D1, D2, 2, 0>(W4p + (size_t)ed * ((D2 / 16) * (D1 / 32) * 512),
                            bd2 + ed * D2, buf1, nullptr, outP, wid, lane);
}

// --------------------------------------------------------------- launch ---
extern "C" void kernel_launch(void* const* d_in, const int* in_sizes, int n_in,
                              void* d_out, int out_size, void* d_ws, size_t ws_size,
                              hipStream_t stream)
{
    constexpr int E = 8, S = 256, H1 = 512, H2 = 256, D1 = 512, D2 = 128;

    const float* inputs = (const float*)d_in[0];
    const int*   sel_s  = (const int*)d_in[1];
    const int*   sel_d  = (const int*)d_in[2];
    const float* Ws1 = (const float*)d_in[3];
    const float* bs1 = (const float*)d_in[4];
    const float* Ws2 = (const float*)d_in[5];
    const float* bs2 = (const float*)d_in[6];
    const float* Wd1 = (const float*)d_in[7];
    const float* bd1 = (const float*)d_in[8];
    const float* Wd2 = (const float*)d_in[9];
    const float* bd2 = (const float*)d_in[10];
    float* out = (float*)d_out;

    // workspace: packed bf16 weights
    ushort* W1p = (ushort*)d_ws;                     // [E] fg:32 s:8  lane j
    ushort* W2p = W1p + (size_t)E * S * H1;
    ushort* W3p = W2p + (size_t)E * H1 * H2;
    ushort* W4p = W3p + (size_t)E * H2 * D1;

    prep_weights<<<dim3(32, E, 4), 256, 0, stream>>>(
        Ws1, Ws2, Wd1, Wd2, W1p, W2p, W3p, W4p);

    madps_fused<<<dim3(256), dim3(1024), 0, stream>>>(
        inputs, sel_s, sel_d, W1p, W2p, W3p, W4p,
        bs1, bs2, bd1, bd2, out);
}

// Round 8
// 34.796 us; speedup vs baseline: 2.2237x; 1.2411x over previous
//
#include <hip/hip_runtime.h>
#include <hip/hip_bf16.h>

// MADPSNet fused, round 8: the CLEAN 4-waves/SIMD TLP test.
// r7 post-mortem: VGPR=64 + WRITE_SIZE 51MB = scratch spill; the hand
// pipeline + sched_barrier blew the 128-VGPR cap 16 resident waves need.
// This round: 16 waves (4/SIMD TLP, m114) + fragment-packed B (contiguous
// coalesced loads) with MINIMAL register demand:
//  - single a[M4]/b[F] buffers, plain unrolled k-loop
//  - no sched_barrier, no setprio, no multibuffering (all proven null/harmful)
// Activations in LDS (96 KB, XOR-swizzled both sides); agent=bid&7 XCD-pin.

typedef __attribute__((ext_vector_type(8))) short bf16x8;
typedef __attribute__((ext_vector_type(4))) float f32x4;

__device__ __forceinline__ ushort f2b(float x) {
    __hip_bfloat16 h = __float2bfloat16(x);
    return *reinterpret_cast<ushort*>(&h);
}

// swizzled LDS byte offset for bf16 (row, col); row stride = LD elems
__device__ __forceinline__ int swz_off(int row, int col, int LD) {
    const int chunk = col >> 3;
    const int phys  = chunk ^ (row & 7);
    return row * (LD * 2) + (phys << 4) + ((col & 7) << 1);
}

// ------------------------------------------------------------------ prep ---
// W[e][K][N] fp32 -> Wp[e][fg][s][lane][j] bf16 (MFMA fragment order):
//   n = fg*16 + (lane&15), k = s*32 + (lane>>4)*8 + j,  s = 0..K/32-1
__global__ __launch_bounds__(256)
void prep_weights(const float* __restrict__ Ws1, const float* __restrict__ Ws2,
                  const float* __restrict__ Wd1, const float* __restrict__ Wd2,
                  ushort* __restrict__ W1p, ushort* __restrict__ W2p,
                  ushort* __restrict__ W3p, ushort* __restrict__ W4p)
{
    const int layer = blockIdx.z;
    const int e  = blockIdx.y;
    const int fg = blockIdx.x;
    const float* W; ushort* Wp; int K, N;
    if (layer == 0)      { W = Ws1; Wp = W1p; K = 256; N = 512; }
    else if (layer == 1) { W = Ws2; Wp = W2p; K = 512; N = 256; }
    else if (layer == 2) { W = Wd1; Wp = W3p; K = 256; N = 512; }
    else                 { W = Wd2; Wp = W4p; K = 512; N = 128; }
    if (fg >= N / 16) return;
    const int NK = K / 32;
    W += (size_t)e * K * N;

    __shared__ float tile[512][17];
    const int tid = threadIdx.x;
    const int n0 = fg * 16;
    for (int idx = tid; idx < K * 16; idx += 256)
        tile[idx >> 4][idx & 15] = W[(size_t)(idx >> 4) * N + n0 + (idx & 15)];
    __syncthreads();
    ushort* dst = Wp + (((size_t)e * (N / 16) + fg) * NK) * 512;
    for (int w = tid; w < NK * 64; w += 256) {
        const int s    = w >> 6;
        const int lane = w & 63;
        const int c    = lane & 15;
        const int kb   = s * 32 + ((lane >> 4) << 3);
        bf16x8 v;
        #pragma unroll
        for (int j = 0; j < 8; ++j)
            v[j] = (short)f2b(tile[kb + j][c]);
        *reinterpret_cast<bf16x8*>(&dst[(size_t)w * 8]) = v;
    }
}

// ----------------------------------------------------------- fused layer ---
// A: LDS [64][K] bf16 swizzled. B: packed global (fragment order).
// 16 waves: MG row-groups x NG col-groups (MG*NG=16), F=N/16/NG frags/wave.
template<int K, int N, int MG, int RELU>
__device__ __forceinline__ void layer_mlp(
    const ushort* __restrict__ Wp, const float* __restrict__ bias,
    const ushort* __restrict__ sIn, ushort* __restrict__ sOut,
    float* __restrict__ gOut, int wid, int lane)
{
    constexpr int NG = 16 / MG;          // col groups
    constexpr int F  = N / 16 / NG;      // frags per wave
    constexpr int M4 = 4 / MG;           // m-frags per wave
    constexpr int NK = K / 32;           // k-steps
    const int r15 = lane & 15, lh = lane >> 4;
    const int wc = wid % NG, wr = wid / NG;
    const int rowBase = wr * (64 / MG);

    const ushort* bBase = Wp + ((size_t)(wc * F) * NK) * 512 + (size_t)lane * 8;

    f32x4 acc[M4][F];
    #pragma unroll
    for (int m = 0; m < M4; ++m)
        #pragma unroll
        for (int f = 0; f < F; ++f)
            acc[m][f] = (f32x4){0.f, 0.f, 0.f, 0.f};

    #pragma unroll
    for (int s = 0; s < NK; ++s) {
        const int k0 = s * 32;
        bf16x8 a[M4];
        #pragma unroll
        for (int m = 0; m < M4; ++m) {
            const int row  = rowBase + m * 16 + r15;
            const int phys = ((k0 >> 3) + lh) ^ (row & 7);
            a[m] = *reinterpret_cast<const bf16x8*>(
                reinterpret_cast<const char*>(sIn) + row * (K * 2) + (phys << 4));
        }
        bf16x8 b[F];
        #pragma unroll
        for (int f = 0; f < F; ++f)
            b[f] = *reinterpret_cast<const bf16x8*>(
                bBase + ((size_t)f * NK + s) * 512);
        #pragma unroll
        for (int m = 0; m < M4; ++m)
            #pragma unroll
            for (int f = 0; f < F; ++f)
                acc[m][f] = __builtin_amdgcn_mfma_f32_16x16x32_bf16(
                    a[m], b[f], acc[m][f], 0, 0, 0);
    }

    // epilogue
    #pragma unroll
    for (int f = 0; f < F; ++f) {
        const int col = (wc * F + f) * 16 + r15;
        const float bv = bias[col];
        #pragma unroll
        for (int m = 0; m < M4; ++m) {
            #pragma unroll
            for (int j = 0; j < 4; ++j) {
                const int row = rowBase + m * 16 + lh * 4 + j;   // C/D (m89)
                float v = acc[m][f][j] + bv;
                if (RELU) v = fmaxf(v, 0.f);
                if (gOut) {
                    gOut[(size_t)row * N + col] = v;
                } else {
                    *reinterpret_cast<ushort*>(
                        reinterpret_cast<char*>(sOut) + swz_off(row, col, N)) = f2b(v);
                }
            }
        }
    }
}

// ----------------------------------------------------------- fused kernel ---
__global__ __launch_bounds__(1024, 4)
void madps_fused(const float* __restrict__ X,
                 const int* __restrict__ sel_s, const int* __restrict__ sel_d,
                 const ushort* __restrict__ W1p, const ushort* __restrict__ W2p,
                 const ushort* __restrict__ W3p, const ushort* __restrict__ W4p,
                 const float* __restrict__ bs1, const float* __restrict__ bs2,
                 const float* __restrict__ bd1, const float* __restrict__ bd2,
                 float* __restrict__ out)
{
    constexpr int S = 256, H1 = 512, H2 = 256, D1 = 512, D2 = 128;

    __shared__ __align__(16) ushort buf0[64 * 256];   // 32 KB: X, then sh
    __shared__ __align__(16) ushort buf1[64 * 512];   // 64 KB: h, then d

    const int bid   = blockIdx.x;
    const int agent = bid & 7;          // agent == XCD -> weights L2-resident
    const int rb    = bid >> 3;         // row-block within agent (0..31)
    const int tid   = threadIdx.x;
    const int lane  = tid & 63;
    const int wid   = tid >> 6;         // 0..15

    const long long es = sel_s[agent];
    const long long ed = sel_d[agent];

    const float* Xa = X + ((size_t)agent * 2048 + (size_t)rb * 64) * S;

    // ---- stage X [64][256] fp32 -> buf0 bf16 (swizzled) ----
    #pragma unroll
    for (int i = 0; i < 4; ++i) {
        const int flat4 = i * 1024 + tid;       // float4 index, 64/row
        const int row = flat4 >> 6;
        const int c4  = flat4 & 63;
        const float4 v = reinterpret_cast<const float4*>(Xa)[flat4];
        ushort4 o;
        o.x = f2b(v.x); o.y = f2b(v.y); o.z = f2b(v.z); o.w = f2b(v.w);
        const int byteoff = (((c4 >> 1) ^ (row & 7)) << 4) | ((c4 & 1) << 3);
        *reinterpret_cast<ushort4*>(
            reinterpret_cast<char*>(buf0) + row * 512 + byteoff) = o;
    }
    __syncthreads();

    // L1: X(buf0, K=256) @ W1p -> relu -> h(buf1, N=512)
    layer_mlp<S, H1, 1, 1>(W1p + (size_t)es * ((H1 / 16) * (S / 32) * 512),
                           bs1 + es * H1, buf0, buf1, nullptr, wid, lane);
    __syncthreads();
    // L2: h(buf1, K=512) @ W2p -> relu -> sh(buf0, N=256)
    layer_mlp<H1, H2, 1, 1>(W2p + (size_t)es * ((H2 / 16) * (H1 / 32) * 512),
                            bs2 + es * H2, buf1, buf0, nullptr, wid, lane);
    __syncthreads();
    // L3: sh(buf0, K=256) @ W3p -> relu -> d(buf1, N=512)
    layer_mlp<H2, D1, 1, 1>(W3p + (size_t)ed * ((D1 / 16) * (H2 / 32) * 512),
                            bd1 + ed * D1, buf0, buf1, nullptr, wid, lane);
    __syncthreads();
    // L4: d(buf1, K=512) @ W4p + bias -> out fp32 [64][128]  (2x8 M-split)
    float* outP = out + ((size_t)agent * 2048 + (size_t)rb * 64) * D2;
    layer_mlp<D1, D2, 2, 0>(W4p + (size_t)ed * ((D2 / 16) * (D1 / 32) * 512),
                            bd2 + ed * D2, buf1, nullptr, outP, wid, lane);
}

// --------------------------------------------------------------- launch ---
extern "C" void kernel_launch(void* const* d_in, const int* in_sizes, int n_in,
                              void* d_out, int out_size, void* d_ws, size_t ws_size,
                              hipStream_t stream)
{
    constexpr int E = 8, S = 256, H1 = 512, H2 = 256, D1 = 512, D2 = 128;

    const float* inputs = (const float*)d_in[0];
    const int*   sel_s  = (const int*)d_in[1];
    const int*   sel_d  = (const int*)d_in[2];
    const float* Ws1 = (const float*)d_in[3];
    const float* bs1 = (const float*)d_in[4];
    const float* Ws2 = (const float*)d_in[5];
    const float* bs2 = (const float*)d_in[6];
    const float* Wd1 = (const float*)d_in[7];
    const float* bd1 = (const float*)d_in[8];
    const float* Wd2 = (const float*)d_in[9];
    const float* bd2 = (const float*)d_in[10];
    float* out = (float*)d_out;

    // workspace: packed bf16 weights
    ushort* W1p = (ushort*)d_ws;
    ushort* W2p = W1p + (size_t)E * S * H1;
    ushort* W3p = W2p + (size_t)E * H1 * H2;
    ushort* W4p = W3p + (size_t)E * H2 * D1;

    prep_weights<<<dim3(32, E, 4), 256, 0, stream>>>(
        Ws1, Ws2, Wd1, Wd2, W1p, W2p, W3p, W4p);

    madps_fused<<<dim3(256), dim3(1024), 0, stream>>>(
        inputs, sel_s, sel_d, W1p, W2p, W3p, W4p,
        bs1, bs2, bd1, bd2, out);
}